// Round 5
// baseline (94.950 us; speedup 1.0000x reference)
//
#include <hip/hip_runtime.h>
#include <hip/hip_bf16.h>
#include <math.h>

// Problem constants (reference: N_NODES=2048, N_ATTRS=64, TOP_K=8)
#define NN 2048
#define NF 64
#define KK 8

// Device-global scratch, fully rewritten by order_kernel each call.
__device__ float    g_xs[NF * NN];   // x values, per-f bucket-descending order
__device__ unsigned g_xi[NF * NN];   // source node index per position
__device__ float    g_sm[NF * NN];   // EXACT suffix max of g_xs (exit bound)

// ---------------- Kernel 1: per-feature approx-descending order -----------
// One 256-thread block per feature. 256-bucket counting sort (monotone map),
// then exact suffix-max. Bucket quality affects only speed, never results.
__global__ __launch_bounds__(256)
void order_kernel(const float* __restrict__ x) {
  __shared__ int   hist[256];
  __shared__ int   scan[256];
  __shared__ int   offs[256];
  __shared__ float svals[NN];
  const int f = blockIdx.x;
  const int tid = threadIdx.x;

  hist[tid] = 0;
  __syncthreads();

  float v[8];
  int   b[8];
#pragma unroll
  for (int k = 0; k < 8; ++k) {
    int e = tid + (k << 8);
    v[k] = x[(size_t)e * NF + f];
    int bb = (int)((3.6f - v[k]) * 35.4f);
    b[k] = bb < 0 ? 0 : (bb > 255 ? 255 : bb);
    atomicAdd(&hist[b[k]], 1);
  }
  __syncthreads();

  // Hillis-Steele inclusive scan over 256 buckets.
  scan[tid] = hist[tid];
  __syncthreads();
  for (int d = 1; d < 256; d <<= 1) {
    int o = (tid >= d) ? scan[tid - d] : 0;
    __syncthreads();
    scan[tid] += o;
    __syncthreads();
  }
  offs[tid] = scan[tid] - hist[tid];   // exclusive
  __syncthreads();

#pragma unroll
  for (int k = 0; k < 8; ++k) {
    int e = tid + (k << 8);
    int p = atomicAdd(&offs[b[k]], 1);
    svals[p] = v[k];
    g_xs[f * NN + p] = v[k];
    g_xi[f * NN + p] = (unsigned)e;
  }
  __syncthreads();

  // Exact suffix max, doubling in LDS (read-all / barrier / write-all).
  for (int d = 1; d < NN; d <<= 1) {
    float o[8];
#pragma unroll
    for (int k = 0; k < 8; ++k) {
      int p = tid + (k << 8);
      o[k] = (p + d < NN) ? svals[p + d] : -INFINITY;
    }
    __syncthreads();
#pragma unroll
    for (int k = 0; k < 8; ++k) {
      int p = tid + (k << 8);
      svals[p] = fmaxf(svals[p], o[k]);
    }
    __syncthreads();
  }
#pragma unroll
  for (int k = 0; k < 8; ++k) {
    int p = tid + (k << 8);
    g_sm[f * NN + p] = svals[p];
  }
}

// ---------------- Kernel 2: pruned, pipelined top-8 scan ------------------
__device__ __forceinline__ void ins8(float (&t)[KK], float p) {
  t[7] = fmaxf(t[7], p);
#pragma unroll
  for (int s = KK - 1; s >= 1; --s) {
    float hi = fmaxf(t[s - 1], t[s]);
    float lo = fminf(t[s - 1], t[s]);
    t[s - 1] = hi;
    t[s] = lo;
  }
}

struct Buf {
  float4 v0, v1;
  uint4  i0, i1;
  float  a[8];
};

__device__ __forceinline__ void loadc(Buf& B, const float* vp, const unsigned* ip,
                                      const float* __restrict__ adj, int j, int pos) {
  B.v0 = *(const float4*)(vp + pos);
  B.v1 = *(const float4*)(vp + pos + 4);
  B.i0 = *(const uint4*)(ip + pos);
  B.i1 = *(const uint4*)(ip + pos + 4);
  B.a[0] = adj[((size_t)B.i0.x << 11) + j];
  B.a[1] = adj[((size_t)B.i0.y << 11) + j];
  B.a[2] = adj[((size_t)B.i0.z << 11) + j];
  B.a[3] = adj[((size_t)B.i0.w << 11) + j];
  B.a[4] = adj[((size_t)B.i1.x << 11) + j];
  B.a[5] = adj[((size_t)B.i1.y << 11) + j];
  B.a[6] = adj[((size_t)B.i1.z << 11) + j];
  B.a[7] = adj[((size_t)B.i1.w << 11) + j];
}

__device__ __forceinline__ void proc(const Buf& B, float (&t8)[KK]) {
  ins8(t8, B.a[0] * B.v0.x);
  ins8(t8, B.a[1] * B.v0.y);
  ins8(t8, B.a[2] * B.v0.z);
  ins8(t8, B.a[3] * B.v0.w);
  ins8(t8, B.a[4] * B.v1.x);
  ins8(t8, B.a[5] * B.v1.y);
  ins8(t8, B.a[6] * B.v1.z);
  ins8(t8, B.a[7] * B.v1.w);
}

// Block = 64 j (lanes) x 4 f x 2 interleaved i-halves = 8 waves.
// Grid = 32 j-tiles x 16 f-groups = 512 blocks -> 2 blocks/CU, 4 waves/SIMD.
// Each wave scans every other 8-chunk of its feature's descending stream,
// prefetching the next chunk BEFORE the exit check so gather latency
// overlaps the insert VALU work. Exit is exact: own 8th-best >= global
// suffix max of all unprocessed positions (adj in [0,1) => a*x <= max(x,0)).
__global__ __launch_bounds__(512, 4)
void topk_kernel(const float* __restrict__ x, const float* __restrict__ adj,
                 float* __restrict__ out) {
  const int tid  = threadIdx.x;
  const int lane = tid & 63;
  const int w    = __builtin_amdgcn_readfirstlane(tid >> 6);  // 0..7, uniform
  const int ff   = w >> 1;             // feature within group
  const int h    = w & 1;              // interleave half
  const int jt   = blockIdx.x & 31;
  const int fg   = blockIdx.x >> 5;    // 0..15
  const int f    = (fg << 2) + ff;
  const int j    = (jt << 6) + lane;

  const float*    vp = g_xs + f * NN;
  const unsigned* ip = g_xi + f * NN;
  const float*    sp = g_sm + f * NN;

  float t8[KK];
#pragma unroll
  for (int s = 0; s < KK; ++s) t8[s] = -INFINITY;

  Buf A, B;
  int t = h << 3;                      // start: 0 or 8
  loadc(A, vp, ip, adj, j, t);
  for (;;) {
    int tn = t + 16;
    bool hn = tn < NN;
    if (hn) loadc(B, vp, ip, adj, j, tn);   // prefetch before exit decision
    proc(A, t8);
    if (!hn) break;
    if (__all(t8[KK - 1] >= fmaxf(sp[tn], 0.0f))) break;
    t = tn;
    tn = t + 16;
    hn = tn < NN;
    if (hn) loadc(A, vp, ip, adj, j, tn);
    proc(B, t8);
    if (!hn) break;
    if (__all(t8[KK - 1] >= fmaxf(sp[tn], 0.0f))) break;
    t = tn;
  }

  // ---- merge the two interleave halves, stage, and write ----
  __shared__ float part[4][2][KK][64];     // [ff][half][slot][lane] 16 KiB
  __shared__ float obuf[KK + 1][64][4];    // [s][j][ff] 9 KiB
#pragma unroll
  for (int s = 0; s < KK; ++s) part[ff][h][s][lane] = t8[s];
  __syncthreads();

  if (tid < 256) {
    const int jl = tid & 63;
    const int fl = tid >> 6;
    float best[KK];
#pragma unroll
    for (int s = 0; s < KK; ++s) best[s] = part[fl][0][s][jl];
#pragma unroll
    for (int s = 0; s < KK; ++s) ins8(best, part[fl][1][s][jl]);
    obuf[0][jl][fl] = x[(size_t)((jt << 6) + jl) * NF + (fg << 2) + fl];
#pragma unroll
    for (int s = 0; s < KK; ++s) obuf[s + 1][jl][fl] = best[s];
  }
  __syncthreads();

  // out[j, s, f0..f0+3] as 16B float4 runs.
  for (int r = tid; r < 64 * (KK + 1); r += 512) {
    int rj = r / (KK + 1);
    int rs = r - rj * (KK + 1);
    float4 vv = *(const float4*)&obuf[rs][rj][0];
    *(float4*)(out + (size_t)((jt << 6) + rj) * ((KK + 1) * NF) +
               rs * NF + (fg << 2)) = vv;
  }
}

extern "C" void kernel_launch(void* const* d_in, const int* in_sizes, int n_in,
                              void* d_out, int out_size, void* d_ws, size_t ws_size,
                              hipStream_t stream) {
  const float* x   = (const float*)d_in[0];   // (2048, 64) f32
  const float* adj = (const float*)d_in[1];   // (2048, 2048) f32
  float* out = (float*)d_out;                 // (2048, 9, 64) f32
  hipLaunchKernelGGL(order_kernel, dim3(NF), dim3(256), 0, stream, x);
  hipLaunchKernelGGL(topk_kernel, dim3(512), dim3(512), 0, stream, x, adj, out);
}